// Round 1
// baseline (3102.847 us; speedup 1.0000x reference)
//
#include <hip/hip_runtime.h>
#include <cstddef>

// B=2, C=256, W=H=64, N=4096, Cq=64
// outputs: res (2*256*4096) then attention (2*4096*4096), fp32

__device__ __forceinline__ float blk_sum256(float v, float* sm) {
#pragma unroll
  for (int o = 32; o > 0; o >>= 1) v += __shfl_down(v, o, 64);
  __syncthreads();
  if ((threadIdx.x & 63) == 0) sm[threadIdx.x >> 6] = v;
  __syncthreads();
  return sm[0] + sm[1] + sm[2] + sm[3];
}

__device__ __forceinline__ float blk_max256(float v, float* sm) {
#pragma unroll
  for (int o = 32; o > 0; o >>= 1) v = fmaxf(v, __shfl_down(v, o, 64));
  __syncthreads();
  if ((threadIdx.x & 63) == 0) sm[threadIdx.x >> 6] = v;
  __syncthreads();
  return fmaxf(fmaxf(sm[0], sm[1]), fmaxf(sm[2], sm[3]));
}

// ---- spectral norm sigma for the 3 weights (h=256 rows each) ----
__global__ __launch_bounds__(256) void sn3_kernel(
    const float* __restrict__ w1, const float* __restrict__ u1,
    const float* __restrict__ w2, const float* __restrict__ u2,
    const float* __restrict__ w3, const float* __restrict__ u3,
    float* __restrict__ inv_out) {
  __shared__ float t[4608];
  __shared__ float red[4];
  const float* W; const float* u; int K;
  if (blockIdx.x == 0)      { W = w1; u = u1; K = 4608; }
  else if (blockIdx.x == 1) { W = w2; u = u2; K = 2304; }
  else                      { W = w3; u = u3; K = 512;  }
  int tid = threadIdx.x;
  // t = W^T u  (columns j, coalesced across threads)
  for (int j = tid; j < K; j += 256) {
    float a = 0.f;
    for (int i = 0; i < 256; ++i) a += W[(size_t)i * K + j] * u[i];
    t[j] = a;
  }
  __syncthreads();
  float ss = 0.f;
  for (int j = tid; j < K; j += 256) ss += t[j] * t[j];
  ss = blk_sum256(ss, red);
  float invn = 1.0f / (sqrtf(ss) + 1e-12f);   // v = t * invn
  // s_i = W[i,:] . v   (thread i = row)
  float a = 0.f;
  const float* Wr = W + (size_t)tid * K;
  for (int j = 0; j < K; ++j) a += Wr[j] * t[j];
  a *= invn;
  float ns2 = blk_sum256(a * a, red);
  if (tid == 0) {
    float n_s = sqrtf(ns2);
    float sigma = ns2 / (n_s + 1e-12f);
    inv_out[blockIdx.x] = 1.0f / sigma;
  }
}

// ---- q = 1x1 conv (Cq=64 x C=256) ----
__global__ __launch_bounds__(256) void qconv_kernel(
    const float* __restrict__ x, const float* __restrict__ qw, float* __restrict__ q) {
  int gid = blockIdx.x;            // b*1024 + cq*16 + ntile
  int ntile = gid & 15;
  int cq = (gid >> 4) & 63;
  int b = gid >> 10;
  int n = (ntile << 8) + threadIdx.x;
  const float* xb = x + ((size_t)b << 20) + n;   // b*256*4096
  const float* wr = qw + cq * 256;
  float acc = 0.f;
#pragma unroll 8
  for (int c = 0; c < 256; ++c) acc += wr[c] * xb[(size_t)c << 12];
  q[(((size_t)(b * 64 + cq)) << 12) + n] = acc;
}

// ---- energy[b,n,m] = sum_k q[b,k,n] q[b,k,m], 64x64 tiles ----
__global__ __launch_bounds__(256) void energy_kernel(
    const float* __restrict__ q, float* __restrict__ att) {
  int b = blockIdx.z;
  int m0 = blockIdx.x * 64, n0 = blockIdx.y * 64;
  __shared__ float Qn[64][65];
  __shared__ float Qm[64][65];
  int tid = threadIdx.x;
  int col = tid & 63;
#pragma unroll
  for (int p = 0; p < 16; ++p) {
    int k = p * 4 + (tid >> 6);
    const float* qr = q + (((size_t)(b * 64 + k)) << 12);
    Qn[k][col] = qr[n0 + col];
    Qm[k][col] = qr[m0 + col];
  }
  __syncthreads();
  int tx = tid & 15, ty = tid >> 4;
  float acc[4][4] = {};
#pragma unroll
  for (int k = 0; k < 64; ++k) {
    float a[4], bb[4];
#pragma unroll
    for (int i = 0; i < 4; ++i) a[i] = Qn[k][ty * 4 + i];
#pragma unroll
    for (int j = 0; j < 4; ++j) bb[j] = Qm[k][tx * 4 + j];
#pragma unroll
    for (int i = 0; i < 4; ++i)
#pragma unroll
      for (int j = 0; j < 4; ++j) acc[i][j] += a[i] * bb[j];
  }
  size_t base = ((size_t)b << 24);
#pragma unroll
  for (int i = 0; i < 4; ++i) {
    size_t off = base + (((size_t)(n0 + ty * 4 + i)) << 12) + m0 + tx * 4;
    float4 o; o.x = acc[i][0]; o.y = acc[i][1]; o.z = acc[i][2]; o.w = acc[i][3];
    *(float4*)&att[off] = o;
  }
}

// ---- softmax over last dim (4096) in place ----
__global__ __launch_bounds__(256) void softmax_kernel(float* __restrict__ att) {
  __shared__ float red[4];
  size_t row = blockIdx.x;
  float* rp = att + (row << 12);
  float4* rp4 = (float4*)rp;
  int tid = threadIdx.x;
  float4 v[4];
#pragma unroll
  for (int i = 0; i < 4; ++i) v[i] = rp4[tid + (i << 8)];
  float mx = -INFINITY;
#pragma unroll
  for (int i = 0; i < 4; ++i) {
    mx = fmaxf(mx, fmaxf(fmaxf(v[i].x, v[i].y), fmaxf(v[i].z, v[i].w)));
  }
  mx = blk_max256(mx, red);
  float s = 0.f;
#pragma unroll
  for (int i = 0; i < 4; ++i) {
    v[i].x = __expf(v[i].x - mx); v[i].y = __expf(v[i].y - mx);
    v[i].z = __expf(v[i].z - mx); v[i].w = __expf(v[i].w - mx);
    s += v[i].x + v[i].y + v[i].z + v[i].w;
  }
  s = blk_sum256(s, red);
  float inv = 1.0f / s;
#pragma unroll
  for (int i = 0; i < 4; ++i) {
    v[i].x *= inv; v[i].y *= inv; v[i].z *= inv; v[i].w *= inv;
    rp4[tid + (i << 8)] = v[i];
  }
}

// ---- fused: out = X A^T, cf = P A^T, epilogues, write concat y ----
#define KC 32
__global__ __launch_bounds__(256) void outcf_kernel(
    const float* __restrict__ x, const float* __restrict__ pre,
    const float* __restrict__ att, const float* __restrict__ mask,
    const float* __restrict__ gamma_p, const float* __restrict__ alpha_p,
    float* __restrict__ y) {
  int b = blockIdx.z;
  int c0 = blockIdx.y * 64;
  int j0 = blockIdx.x * 64;
  __shared__ float As[64][KC + 1];
  __shared__ float Xs[64][KC + 1];
  __shared__ float Ps[64][KC + 1];
  float accO[4][4] = {}, accC[4][4] = {};
  int tid = threadIdx.x;
  int tx = tid & 15, ty = tid >> 4;
  const float* Ab = att + ((size_t)b << 24);
  const float* Xb = x + ((size_t)b << 20);
  const float* Pb = pre + ((size_t)b << 20);
  int f = tid & 7, r = tid >> 3;
  for (int k0 = 0; k0 < 4096; k0 += KC) {
#pragma unroll
    for (int p = 0; p < 2; ++p) {
      int row = r + p * 32;
      float4 av = *(const float4*)&Ab[(((size_t)(j0 + row)) << 12) + k0 + f * 4];
      float4 xv = *(const float4*)&Xb[(((size_t)(c0 + row)) << 12) + k0 + f * 4];
      float4 pv = *(const float4*)&Pb[(((size_t)(c0 + row)) << 12) + k0 + f * 4];
      float* da = &As[row][f * 4]; da[0]=av.x; da[1]=av.y; da[2]=av.z; da[3]=av.w;
      float* dx = &Xs[row][f * 4]; dx[0]=xv.x; dx[1]=xv.y; dx[2]=xv.z; dx[3]=xv.w;
      float* dp = &Ps[row][f * 4]; dp[0]=pv.x; dp[1]=pv.y; dp[2]=pv.z; dp[3]=pv.w;
    }
    __syncthreads();
#pragma unroll
    for (int kk = 0; kk < KC; ++kk) {
      float a[4], c2[4], bb[4];
#pragma unroll
      for (int i = 0; i < 4; ++i) a[i] = Xs[ty * 4 + i][kk];
#pragma unroll
      for (int i = 0; i < 4; ++i) c2[i] = Ps[ty * 4 + i][kk];
#pragma unroll
      for (int j = 0; j < 4; ++j) bb[j] = As[tx * 4 + j][kk];
#pragma unroll
      for (int i = 0; i < 4; ++i)
#pragma unroll
        for (int j = 0; j < 4; ++j) {
          accO[i][j] += a[i] * bb[j];
          accC[i][j] += c2[i] * bb[j];
        }
    }
    __syncthreads();
  }
  float g = gamma_p[0], al = alpha_p[0];
  int jb = j0 + tx * 4;
  float4 mv = *(const float4*)&mask[((size_t)b << 12) + jb];
#pragma unroll
  for (int i = 0; i < 4; ++i) {
    int cc = c0 + ty * 4 + i;
    size_t off = (((size_t)(b * 256 + cc)) << 12) + jb;
    float4 xv = *(const float4*)&x[off];
    float4 pv = *(const float4*)&pre[off];
    float4 o1, o2;
    o1.x = g * accO[i][0] + xv.x; o1.y = g * accO[i][1] + xv.y;
    o1.z = g * accO[i][2] + xv.z; o1.w = g * accO[i][3] + xv.w;
    o2.x = al * (1.f - mv.x) * accC[i][0] + mv.x * pv.x;
    o2.y = al * (1.f - mv.y) * accC[i][1] + mv.y * pv.y;
    o2.z = al * (1.f - mv.z) * accC[i][2] + mv.z * pv.z;
    o2.w = al * (1.f - mv.w) * accC[i][3] + mv.w * pv.w;
    *(float4*)&y[(((size_t)(b * 512 + cc)) << 12) + jb] = o1;
    *(float4*)&y[(((size_t)(b * 512 + 256 + cc)) << 12) + jb] = o2;
  }
}

// ---- BN training-mode stats per channel over (B, N) ----
__global__ __launch_bounds__(256) void bn_stats_kernel(
    const float* __restrict__ t, float* __restrict__ mean, float* __restrict__ rstd, int C) {
  __shared__ float red[4];
  int ch = blockIdx.x;
  float s = 0.f, ss = 0.f;
  for (int b = 0; b < 2; ++b) {
    const float* p = t + (((size_t)(b * C + ch)) << 12);
    for (int n = threadIdx.x; n < 4096; n += 256) { float v = p[n]; s += v; ss += v * v; }
  }
  s = blk_sum256(s, red);
  ss = blk_sum256(ss, red);
  if (threadIdx.x == 0) {
    float m = s * (1.0f / 8192.0f);
    float var = ss * (1.0f / 8192.0f) - m * m;
    mean[ch] = m;
    rstd[ch] = rsqrtf(var + 1e-5f);
  }
}

// ---- BN apply + leaky relu (elementwise float4) ----
__global__ __launch_bounds__(256) void bn_act_kernel(
    const float* __restrict__ src, float* __restrict__ dst,
    const float* __restrict__ mean, const float* __restrict__ rstd,
    const float* __restrict__ sc, const float* __restrict__ bi, int C, int total4) {
  int i = blockIdx.x * 256 + threadIdx.x;
  if (i >= total4) return;
  int ch = (i >> 10) % C;
  float a = rstd[ch] * sc[ch];
  float bb = bi[ch] - mean[ch] * a;
  float4 v = ((const float4*)src)[i];
  float4 o;
  o.x = v.x * a + bb; o.x = o.x > 0.f ? o.x : 0.01f * o.x;
  o.y = v.y * a + bb; o.y = o.y > 0.f ? o.y : 0.01f * o.y;
  o.z = v.z * a + bb; o.z = o.z > 0.f ? o.z : 0.01f * o.z;
  o.w = v.w * a + bb; o.w = o.w > 0.f ? o.w : 0.01f * o.w;
  ((float4*)dst)[i] = o;
}

// ---- 3x3 conv, pad 1; 32x32 pixel tile (2x2/thread), 4 co/block ----
__global__ __launch_bounds__(256) void conv3x3_kernel(
    const float* __restrict__ src, const float* __restrict__ w,
    const float* __restrict__ inv_sig, int sig_idx, int Cin, int Cout,
    float* __restrict__ out, const float* __restrict__ addsrc) {
  int b = blockIdx.z;
  int co0 = blockIdx.y * 4;
  int t0 = blockIdx.x;
  int ty0 = (t0 >> 1) * 32, tx0 = (t0 & 1) * 32;
  __shared__ float at[34 * 35];
  __shared__ float wt[36];
  int tid = threadIdx.x;
  int qx = (tid & 15) * 2, qy = (tid >> 4) * 2;
  float acc[4][4] = {};
  for (int ci = 0; ci < Cin; ++ci) {
    const float* ap = src + (((size_t)(b * Cin + ci)) << 12);
    for (int li = tid; li < 1156; li += 256) {
      int ly = li / 34, lx = li - ly * 34;
      int ay = ty0 + ly - 1, ax = tx0 + lx - 1;
      at[ly * 35 + lx] = ((unsigned)ay < 64u && (unsigned)ax < 64u) ? ap[(ay << 6) + ax] : 0.f;
    }
    if (tid < 36) {
      int o = tid / 9, t = tid - o * 9;
      wt[tid] = w[(((size_t)(co0 + o)) * Cin + ci) * 9 + t];
    }
    __syncthreads();
    float a[4][4];
#pragma unroll
    for (int rr = 0; rr < 4; ++rr)
#pragma unroll
      for (int cc = 0; cc < 4; ++cc) a[rr][cc] = at[(qy + rr) * 35 + qx + cc];
#pragma unroll
    for (int o = 0; o < 4; ++o) {
      const float* wo = wt + o * 9;
#pragma unroll
      for (int kr = 0; kr < 3; ++kr)
#pragma unroll
        for (int kc = 0; kc < 3; ++kc) {
          float wv = wo[kr * 3 + kc];
          acc[o][0] += a[kr][kc] * wv;
          acc[o][1] += a[kr][kc + 1] * wv;
          acc[o][2] += a[kr + 1][kc] * wv;
          acc[o][3] += a[kr + 1][kc + 1] * wv;
        }
    }
    __syncthreads();
  }
  float isg = inv_sig[sig_idx];
#pragma unroll
  for (int o = 0; o < 4; ++o) {
    int co = co0 + o;
    size_t base = (((size_t)(b * Cout + co)) << 12);
    int y0 = ty0 + qy, x0 = tx0 + qx;
    size_t p00 = base + (y0 << 6) + x0;
    float v0 = acc[o][0] * isg, v1 = acc[o][1] * isg;
    float v2 = acc[o][2] * isg, v3 = acc[o][3] * isg;
    if (addsrc) { v0 += addsrc[p00]; v1 += addsrc[p00 + 1]; v2 += addsrc[p00 + 64]; v3 += addsrc[p00 + 65]; }
    out[p00] = v0; out[p00 + 1] = v1; out[p00 + 64] = v2; out[p00 + 65] = v3;
  }
}

// ---- shortcut 1x1 conv (512->256) as tiled GEMM, writes res ----
__global__ __launch_bounds__(256) void scgemm_kernel(
    const float* __restrict__ y, const float* __restrict__ w,
    const float* __restrict__ inv_sig, float* __restrict__ res) {
  int b = blockIdx.z;
  int co0 = blockIdx.y * 64;
  int n0 = blockIdx.x * 64;
  __shared__ float Ws[64][33];
  __shared__ float Ys[32][65];
  float acc[4][4] = {};
  int tid = threadIdx.x;
  int tx = tid & 15, ty = tid >> 4;
  for (int k0 = 0; k0 < 512; k0 += 32) {
    int f = tid & 7, r = tid >> 3;
#pragma unroll
    for (int p = 0; p < 2; ++p) {
      int co = r + p * 32;
      float4 wv = *(const float4*)&w[((size_t)(co0 + co)) * 512 + k0 + f * 4];
      float* d = &Ws[co][f * 4]; d[0]=wv.x; d[1]=wv.y; d[2]=wv.z; d[3]=wv.w;
    }
#pragma unroll
    for (int p = 0; p < 2; ++p) {
      int k = (tid >> 4) + p * 16;
      float4 v = *(const float4*)&y[(((size_t)(b * 512 + k0 + k)) << 12) + n0 + (tid & 15) * 4];
      float* d = &Ys[k][(tid & 15) * 4]; d[0]=v.x; d[1]=v.y; d[2]=v.z; d[3]=v.w;
    }
    __syncthreads();
#pragma unroll
    for (int kk = 0; kk < 32; ++kk) {
      float wv[4], yv[4];
#pragma unroll
      for (int i = 0; i < 4; ++i) wv[i] = Ws[ty * 4 + i][kk];
#pragma unroll
      for (int j = 0; j < 4; ++j) yv[j] = Ys[kk][tx * 4 + j];
#pragma unroll
      for (int i = 0; i < 4; ++i)
#pragma unroll
        for (int j = 0; j < 4; ++j) acc[i][j] += wv[i] * yv[j];
    }
    __syncthreads();
  }
  float isg = inv_sig[2];
#pragma unroll
  for (int i = 0; i < 4; ++i) {
    int co = co0 + ty * 4 + i;
    size_t base = (((size_t)(b * 256 + co)) << 12) + n0 + tx * 4;
    float4 o;
    o.x = acc[i][0] * isg; o.y = acc[i][1] * isg;
    o.z = acc[i][2] * isg; o.w = acc[i][3] * isg;
    *(float4*)&res[base] = o;
  }
}

extern "C" void kernel_launch(void* const* d_in, const int* in_sizes, int n_in,
                              void* d_out, int out_size, void* d_ws, size_t ws_size,
                              hipStream_t stream) {
  const float* x     = (const float*)d_in[0];
  const float* pre   = (const float*)d_in[1];
  const float* mask  = (const float*)d_in[2];
  const float* qw    = (const float*)d_in[3];
  const float* gamma = (const float*)d_in[4];
  const float* alpha = (const float*)d_in[5];
  const float* bn1s  = (const float*)d_in[6];
  const float* bn1b  = (const float*)d_in[7];
  const float* c1w   = (const float*)d_in[8];
  const float* u1    = (const float*)d_in[9];
  const float* bn2s  = (const float*)d_in[11];
  const float* bn2b  = (const float*)d_in[12];
  const float* c2w   = (const float*)d_in[13];
  const float* u2    = (const float*)d_in[14];
  const float* byw   = (const float*)d_in[16];
  const float* u3    = (const float*)d_in[17];

  float* res = (float*)d_out;                 // 2*256*4096
  float* att = res + (size_t)2 * 256 * 4096;  // 2*4096*4096

  float* wsf = (float*)d_ws;
  float* inv_sig = wsf + 0;          // 3
  float* mean1   = wsf + 16;         // 512
  float* rstd1   = wsf + 528;        // 512
  float* mean2   = wsf + 1040;       // 256
  float* rstd2   = wsf + 1296;       // 256
  float* q       = wsf + 2048;       // 524288
  float* y       = wsf + 526336;     // 4194304
  float* act     = wsf + 4720640;    // 4194304
  float* h1      = wsf + 8914944;    // 2097152
  float* act2    = wsf + 11012096;   // 2097152

  hipLaunchKernelGGL(sn3_kernel, dim3(3), dim3(256), 0, stream,
                     c1w, u1, c2w, u2, byw, u3, inv_sig);
  hipLaunchKernelGGL(qconv_kernel, dim3(2048), dim3(256), 0, stream, x, qw, q);
  hipLaunchKernelGGL(energy_kernel, dim3(64, 64, 2), dim3(256), 0, stream, q, att);
  hipLaunchKernelGGL(softmax_kernel, dim3(8192), dim3(256), 0, stream, att);
  hipLaunchKernelGGL(outcf_kernel, dim3(64, 4, 2), dim3(256), 0, stream,
                     x, pre, att, mask, gamma, alpha, y);
  hipLaunchKernelGGL(bn_stats_kernel, dim3(512), dim3(256), 0, stream, y, mean1, rstd1, 512);
  hipLaunchKernelGGL(bn_act_kernel, dim3(4096), dim3(256), 0, stream,
                     y, act, mean1, rstd1, bn1s, bn1b, 512, 1048576);
  hipLaunchKernelGGL(conv3x3_kernel, dim3(4, 64, 2), dim3(256), 0, stream,
                     act, c1w, inv_sig, 0, 512, 256, h1, (const float*)nullptr);
  hipLaunchKernelGGL(bn_stats_kernel, dim3(256), dim3(256), 0, stream, h1, mean2, rstd2, 256);
  hipLaunchKernelGGL(bn_act_kernel, dim3(2048), dim3(256), 0, stream,
                     h1, act2, mean2, rstd2, bn2s, bn2b, 256, 524288);
  hipLaunchKernelGGL(scgemm_kernel, dim3(64, 4, 2), dim3(256), 0, stream, y, byw, inv_sig, res);
  hipLaunchKernelGGL(conv3x3_kernel, dim3(4, 64, 2), dim3(256), 0, stream,
                     act2, c2w, inv_sig, 1, 256, 256, res, res);
}

// Round 2
// 1268.852 us; speedup vs baseline: 2.4454x; 2.4454x over previous
//
#include <hip/hip_runtime.h>
#include <cstddef>

// B=2, C=256, W=H=64, N=4096, Cq=64
// outputs: res (2*256*4096) then attention (2*4096*4096), fp32

typedef __attribute__((ext_vector_type(8))) short bh8;   // 8 bf16 (4 VGPR)
typedef __attribute__((ext_vector_type(4))) short bh4;   // 4 bf16 (8B)
typedef __attribute__((ext_vector_type(4))) float f4;    // MFMA acc

static __device__ __forceinline__ short f2bf(float f) {
  unsigned u = __float_as_uint(f);
  unsigned r = (u + 0x7fffu + ((u >> 16) & 1u)) >> 16;
  return (short)r;
}
static __device__ __forceinline__ float bf2f(unsigned short s) {
  return __uint_as_float(((unsigned)s) << 16);
}

__device__ __forceinline__ float blk_sum256(float v, float* sm) {
#pragma unroll
  for (int o = 32; o > 0; o >>= 1) v += __shfl_down(v, o, 64);
  __syncthreads();
  if ((threadIdx.x & 63) == 0) sm[threadIdx.x >> 6] = v;
  __syncthreads();
  return sm[0] + sm[1] + sm[2] + sm[3];
}

__device__ __forceinline__ float blk_max256(float v, float* sm) {
#pragma unroll
  for (int o = 32; o > 0; o >>= 1) v = fmaxf(v, __shfl_down(v, o, 64));
  __syncthreads();
  if ((threadIdx.x & 63) == 0) sm[threadIdx.x >> 6] = v;
  __syncthreads();
  return fmaxf(fmaxf(sm[0], sm[1]), fmaxf(sm[2], sm[3]));
}

// ---- spectral norm sigma (f32, exact) ----
__global__ __launch_bounds__(256) void sn3_kernel(
    const float* __restrict__ w1, const float* __restrict__ u1,
    const float* __restrict__ w2, const float* __restrict__ u2,
    const float* __restrict__ w3, const float* __restrict__ u3,
    float* __restrict__ inv_out) {
  __shared__ float t[4608];
  __shared__ float red[4];
  const float* W; const float* u; int K;
  if (blockIdx.x == 0)      { W = w1; u = u1; K = 4608; }
  else if (blockIdx.x == 1) { W = w2; u = u2; K = 2304; }
  else                      { W = w3; u = u3; K = 512;  }
  int tid = threadIdx.x;
  for (int j = tid; j < K; j += 256) {
    float a = 0.f;
    for (int i = 0; i < 256; ++i) a += W[(size_t)i * K + j] * u[i];
    t[j] = a;
  }
  __syncthreads();
  float ss = 0.f;
  for (int j = tid; j < K; j += 256) ss += t[j] * t[j];
  ss = blk_sum256(ss, red);
  float invn = 1.0f / (sqrtf(ss) + 1e-12f);
  float a = 0.f;
  const float* Wr = W + (size_t)tid * K;
  for (int j = 0; j < K; ++j) a += Wr[j] * t[j];
  a *= invn;
  float ns2 = blk_sum256(a * a, red);
  if (tid == 0) {
    float n_s = sqrtf(ns2);
    float sigma = ns2 / (n_s + 1e-12f);
    inv_out[blockIdx.x] = 1.0f / sigma;
  }
}

// ---- cast x / pre to bf16 (same [c][n] layout) ----
__global__ __launch_bounds__(256) void cast_xp_kernel(
    const float* __restrict__ x, const float* __restrict__ pre,
    unsigned short* __restrict__ xb, unsigned short* __restrict__ pb) {
  int i = blockIdx.x * 256 + threadIdx.x;   // 8 elems per thread
  const float* s = blockIdx.y ? pre : x;
  unsigned short* d = blockIdx.y ? pb : xb;
  float4 v0 = ((const float4*)s)[i * 2];
  float4 v1 = ((const float4*)s)[i * 2 + 1];
  bh8 o = { f2bf(v0.x), f2bf(v0.y), f2bf(v0.z), f2bf(v0.w),
            f2bf(v1.x), f2bf(v1.y), f2bf(v1.z), f2bf(v1.w) };
  *(bh8*)&d[(size_t)i * 8] = o;
}

// ---- transpose conv weights OIHW -> [tap][co][ci], bf16 ----
__global__ __launch_bounds__(256) void transpose_w_kernel(
    const float* __restrict__ src, unsigned short* __restrict__ dst, int Cin) {
  int i = blockIdx.x * 256 + threadIdx.x;   // linear over 9*256*Cin
  int ci = i % Cin;
  int co = (i / Cin) & 255;
  int t = i / (Cin * 256);
  dst[i] = (unsigned short)f2bf(src[((size_t)co * Cin + ci) * 9 + t]);
}

// ---- cast by_w [256][512] to bf16 ----
__global__ __launch_bounds__(256) void cast_w3_kernel(
    const float* __restrict__ src, unsigned short* __restrict__ dst) {
  int i = blockIdx.x * 256 + threadIdx.x;   // 8 elems per thread
  float4 v0 = ((const float4*)src)[i * 2];
  float4 v1 = ((const float4*)src)[i * 2 + 1];
  bh8 o = { f2bf(v0.x), f2bf(v0.y), f2bf(v0.z), f2bf(v0.w),
            f2bf(v1.x), f2bf(v1.y), f2bf(v1.z), f2bf(v1.w) };
  *(bh8*)&dst[(size_t)i * 8] = o;
}

// ---- q = 1x1 conv (f32) ----
__global__ __launch_bounds__(256) void qconv_kernel(
    const float* __restrict__ x, const float* __restrict__ qw, float* __restrict__ q) {
  int gid = blockIdx.x;
  int ntile = gid & 15;
  int cq = (gid >> 4) & 63;
  int b = gid >> 10;
  int n = (ntile << 8) + threadIdx.x;
  const float* xb = x + ((size_t)b << 20) + n;
  const float* wr = qw + cq * 256;
  float acc = 0.f;
#pragma unroll 8
  for (int c = 0; c < 256; ++c) acc += wr[c] * xb[(size_t)c << 12];
  q[(((size_t)(b * 64 + cq)) << 12) + n] = acc;
}

// ---- energy (f32, exact since attention is a checked output) ----
__global__ __launch_bounds__(256) void energy_kernel(
    const float* __restrict__ q, float* __restrict__ att) {
  int b = blockIdx.z;
  int m0 = blockIdx.x * 64, n0 = blockIdx.y * 64;
  __shared__ float Qn[64][65];
  __shared__ float Qm[64][65];
  int tid = threadIdx.x;
  int col = tid & 63;
#pragma unroll
  for (int p = 0; p < 16; ++p) {
    int k = p * 4 + (tid >> 6);
    const float* qr = q + (((size_t)(b * 64 + k)) << 12);
    Qn[k][col] = qr[n0 + col];
    Qm[k][col] = qr[m0 + col];
  }
  __syncthreads();
  int tx = tid & 15, ty = tid >> 4;
  float acc[4][4] = {};
#pragma unroll
  for (int k = 0; k < 64; ++k) {
    float a[4], bb[4];
#pragma unroll
    for (int i = 0; i < 4; ++i) a[i] = Qn[k][ty * 4 + i];
#pragma unroll
    for (int j = 0; j < 4; ++j) bb[j] = Qm[k][tx * 4 + j];
#pragma unroll
    for (int i = 0; i < 4; ++i)
#pragma unroll
      for (int j = 0; j < 4; ++j) acc[i][j] += a[i] * bb[j];
  }
  size_t base = ((size_t)b << 24);
#pragma unroll
  for (int i = 0; i < 4; ++i) {
    size_t off = base + (((size_t)(n0 + ty * 4 + i)) << 12) + m0 + tx * 4;
    float4 o; o.x = acc[i][0]; o.y = acc[i][1]; o.z = acc[i][2]; o.w = acc[i][3];
    *(float4*)&att[off] = o;
  }
}

// ---- softmax in place over last dim 4096 ----
__global__ __launch_bounds__(256) void softmax_kernel(float* __restrict__ att) {
  __shared__ float red[4];
  size_t row = blockIdx.x;
  float4* rp4 = (float4*)(att + (row << 12));
  int tid = threadIdx.x;
  float4 v[4];
#pragma unroll
  for (int i = 0; i < 4; ++i) v[i] = rp4[tid + (i << 8)];
  float mx = -INFINITY;
#pragma unroll
  for (int i = 0; i < 4; ++i)
    mx = fmaxf(mx, fmaxf(fmaxf(v[i].x, v[i].y), fmaxf(v[i].z, v[i].w)));
  mx = blk_max256(mx, red);
  float s = 0.f;
#pragma unroll
  for (int i = 0; i < 4; ++i) {
    v[i].x = __expf(v[i].x - mx); v[i].y = __expf(v[i].y - mx);
    v[i].z = __expf(v[i].z - mx); v[i].w = __expf(v[i].w - mx);
    s += v[i].x + v[i].y + v[i].z + v[i].w;
  }
  s = blk_sum256(s, red);
  float inv = 1.0f / s;
#pragma unroll
  for (int i = 0; i < 4; ++i) {
    v[i].x *= inv; v[i].y *= inv; v[i].z *= inv; v[i].w *= inv;
    rp4[tid + (i << 8)] = v[i];
  }
}

// ---- fused out/cf MFMA GEMM: 1 wave per block, 64c x 64j tile ----
// A = X (or P) [c][k] bf16, B = att[j][k] f32->bf16 on the fly.
// Writes y_t[b][pixel][512] bf16 (out -> ch 0..255, cf -> 256..511).
__global__ __launch_bounds__(64, 2) void outcf_mfma_kernel(
    const unsigned short* __restrict__ xb, const unsigned short* __restrict__ pb,
    const float* __restrict__ x, const float* __restrict__ pre,
    const float* __restrict__ att, const float* __restrict__ mask,
    const float* __restrict__ gamma_p, const float* __restrict__ alpha_p,
    unsigned short* __restrict__ y_t) {
  int b = blockIdx.z;
  int c0 = blockIdx.y * 64;
  int j0 = blockIdx.x * 64;
  __shared__ short Xs[64 * 40];
  __shared__ short Ps[64 * 40];
  __shared__ short As[64 * 40];
  int lane = threadIdx.x;
  int ln = lane & 15, qd = lane >> 4;
  f4 z = {0.f, 0.f, 0.f, 0.f};
  f4 accO[4][4], accC[4][4];
#pragma unroll
  for (int i = 0; i < 4; ++i)
#pragma unroll
    for (int j = 0; j < 4; ++j) { accO[i][j] = z; accC[i][j] = z; }
  int part = lane & 3, r4 = lane >> 2;
  int part8 = lane & 7, r8 = lane >> 3;
  for (int k0 = 0; k0 < 4096; k0 += 32) {
#pragma unroll
    for (int it = 0; it < 4; ++it) {
      int rr = r4 + it * 16;
      bh8 xv = *(const bh8*)&xb[((size_t)(b * 256 + c0 + rr) << 12) + k0 + part * 8];
      bh8 pv = *(const bh8*)&pb[((size_t)(b * 256 + c0 + rr) << 12) + k0 + part * 8];
      *(bh8*)&Xs[rr * 40 + part * 8] = xv;
      *(bh8*)&Ps[rr * 40 + part * 8] = pv;
    }
#pragma unroll
    for (int it = 0; it < 8; ++it) {
      int rr = r8 + it * 8;
      float4 v = *(const float4*)&att[((size_t)b << 24) + ((size_t)(j0 + rr) << 12) + k0 + part8 * 4];
      bh4 o = { f2bf(v.x), f2bf(v.y), f2bf(v.z), f2bf(v.w) };
      *(bh4*)&As[rr * 40 + part8 * 4] = o;
    }
    __syncthreads();
    bh8 bf[4];
#pragma unroll
    for (int j = 0; j < 4; ++j)
      bf[j] = *(const bh8*)&As[(j * 16 + ln) * 40 + qd * 8];
#pragma unroll
    for (int i = 0; i < 4; ++i) {
      bh8 ax = *(const bh8*)&Xs[(i * 16 + ln) * 40 + qd * 8];
      bh8 ap = *(const bh8*)&Ps[(i * 16 + ln) * 40 + qd * 8];
#pragma unroll
      for (int j = 0; j < 4; ++j) {
        accO[i][j] = __builtin_amdgcn_mfma_f32_16x16x32_bf16(ax, bf[j], accO[i][j], 0, 0, 0);
        accC[i][j] = __builtin_amdgcn_mfma_f32_16x16x32_bf16(ap, bf[j], accC[i][j], 0, 0, 0);
      }
    }
    __syncthreads();
  }
  float g = gamma_p[0], al = alpha_p[0];
#pragma unroll
  for (int j = 0; j < 4; ++j) {
    int jp = j0 + j * 16 + ln;
    float mv = mask[(b << 12) + jp];
#pragma unroll
    for (int i = 0; i < 4; ++i) {
      int cb = c0 + i * 16 + qd * 4;
      bh4 oY, oC;
#pragma unroll
      for (int r = 0; r < 4; ++r) {
        float xo = x[((size_t)(b * 256 + cb + r) << 12) + jp];
        float po = pre[((size_t)(b * 256 + cb + r) << 12) + jp];
        oY[r] = f2bf(g * accO[i][j][r] + xo);
        oC[r] = f2bf(al * (1.f - mv) * accC[i][j][r] + mv * po);
      }
      size_t rowb = ((size_t)b * 4096 + jp) * 512;
      *(bh4*)&y_t[rowb + cb] = oY;
      *(bh4*)&y_t[rowb + 256 + cb] = oC;
    }
  }
}

// ---- BN stats phase 1: per-slab partial sums over [rows][C] ----
__global__ __launch_bounds__(256) void bn_part_kernel(
    const void* __restrict__ src, int isbf, int C, int rows_per_slab,
    float* __restrict__ part) {
  int slab = blockIdx.x;
  int r0 = slab * rows_per_slab;
  for (int co = threadIdx.x; co < C; co += 256) {
    float s = 0.f, ss = 0.f;
    if (isbf) {
      const unsigned short* p = (const unsigned short*)src;
      for (int r = 0; r < rows_per_slab; ++r) {
        float v = bf2f(p[(size_t)(r0 + r) * C + co]); s += v; ss += v * v;
      }
    } else {
      const float* p = (const float*)src;
      for (int r = 0; r < rows_per_slab; ++r) {
        float v = p[(size_t)(r0 + r) * C + co]; s += v; ss += v * v;
      }
    }
    part[(size_t)(slab * 2) * C + co] = s;
    part[(size_t)(slab * 2 + 1) * C + co] = ss;
  }
}

// ---- BN stats phase 2 ----
__global__ __launch_bounds__(256) void bn_finish_kernel(
    const float* __restrict__ part, int C, int slabs, float inv_count,
    float* __restrict__ mean, float* __restrict__ rstd) {
  for (int co = threadIdx.x; co < C; co += 256) {
    float s = 0.f, ss = 0.f;
    for (int sl = 0; sl < slabs; ++sl) {
      s += part[(size_t)(sl * 2) * C + co];
      ss += part[(size_t)(sl * 2 + 1) * C + co];
    }
    float m = s * inv_count;
    float var = ss * inv_count - m * m;
    mean[co] = m;
    rstd[co] = rsqrtf(var + 1e-5f);
  }
}

// ---- BN apply + leaky, bf16 -> bf16 ([n][C] layout) ----
__global__ __launch_bounds__(256) void bn_act_bf_kernel(
    const unsigned short* __restrict__ src, unsigned short* __restrict__ dst,
    const float* __restrict__ mean, const float* __restrict__ rstd,
    const float* __restrict__ sc, const float* __restrict__ bi, int Cm1) {
  int i = blockIdx.x * 256 + threadIdx.x;   // 4 elems
  int ch = (i * 4) & Cm1;
  bh4 v = *(const bh4*)&src[(size_t)i * 4];
  bh4 o;
#pragma unroll
  for (int e = 0; e < 4; ++e) {
    int c = ch + e;
    float a = rstd[c] * sc[c];
    float bb = bi[c] - mean[c] * a;
    float f = bf2f((unsigned short)v[e]) * a + bb;
    f = f > 0.f ? f : 0.01f * f;
    o[e] = f2bf(f);
  }
  *(bh4*)&dst[(size_t)i * 4] = o;
}

// ---- BN apply + leaky, f32 -> bf16 ----
__global__ __launch_bounds__(256) void bn_act_f_kernel(
    const float* __restrict__ src, unsigned short* __restrict__ dst,
    const float* __restrict__ mean, const float* __restrict__ rstd,
    const float* __restrict__ sc, const float* __restrict__ bi, int Cm1) {
  int i = blockIdx.x * 256 + threadIdx.x;   // 4 elems
  int ch = (i * 4) & Cm1;
  float4 v = ((const float4*)src)[i];
  float vv[4] = {v.x, v.y, v.z, v.w};
  bh4 o;
#pragma unroll
  for (int e = 0; e < 4; ++e) {
    int c = ch + e;
    float a = rstd[c] * sc[c];
    float bb = bi[c] - mean[c] * a;
    float f = vv[e] * a + bb;
    f = f > 0.f ? f : 0.01f * f;
    o[e] = f2bf(f);
  }
  *(bh4*)&dst[(size_t)i * 4] = o;
}

// ---- 3x3 conv as 9 accumulated MFMA GEMMs over flat-shifted rows ----
// act_t: [b][4096][Cin] bf16; wt: [9][256][Cin] bf16.
// mode 0: h1_t[b][n][256] = acc*isg (f32). mode 1: res[b][co][n] += acc*isg.
__global__ __launch_bounds__(64, 2) void conv3x3_mfma_kernel(
    const unsigned short* __restrict__ act_t, const unsigned short* __restrict__ wt,
    const float* __restrict__ inv_sig, int sidx, int Cin, int mode,
    float* __restrict__ out) {
  int b = blockIdx.z;
  int co0 = blockIdx.y * 64;
  int n0 = blockIdx.x * 64;
  __shared__ short act_s[194 * 40];
  int lane = threadIdx.x;
  int ln = lane & 15, qd = lane >> 4;
  int part = lane & 3, r4 = lane >> 2;
  f4 z = {0.f, 0.f, 0.f, 0.f};
  f4 acc[4][4];
#pragma unroll
  for (int i = 0; i < 4; ++i)
#pragma unroll
    for (int j = 0; j < 4; ++j) acc[i][j] = z;
  bh8 zf = {};
  int nchunk = Cin >> 5;
  for (int cc = 0; cc < nchunk; ++cc) {
    int ci0 = cc << 5;
#pragma unroll
    for (int it = 0; it < 13; ++it) {
      int rr = r4 + it * 16;
      if (rr < 194) {
        int flat = n0 - 65 + rr;
        bh8 v = {};
        if ((unsigned)flat < 4096u)
          v = *(const bh8*)&act_t[((size_t)(b * 4096 + flat)) * Cin + ci0 + part * 8];
        *(bh8*)&act_s[rr * 40 + part * 8] = v;
      }
    }
    __syncthreads();
#pragma unroll
    for (int t = 0; t < 9; ++t) {
      int dy = t / 3, dx = t - dy * 3;
      int off = (dy - 1) * 64 + (dx - 1);
      bh8 bw[4];
#pragma unroll
      for (int j = 0; j < 4; ++j) {
        int co = co0 + j * 16 + ln;
        bw[j] = *(const bh8*)&wt[((size_t)(t * 256 + co)) * Cin + ci0 + qd * 8];
      }
#pragma unroll
      for (int i = 0; i < 4; ++i) {
        int px = i * 16 + ln;
        bh8 a = *(const bh8*)&act_s[(65 + off + px) * 40 + qd * 8];
        if (dx == 0 && px == 0) a = zf;
        if (dx == 2 && px == 63) a = zf;
#pragma unroll
        for (int j = 0; j < 4; ++j)
          acc[i][j] = __builtin_amdgcn_mfma_f32_16x16x32_bf16(a, bw[j], acc[i][j], 0, 0, 0);
      }
    }
    __syncthreads();
  }
  float isg = inv_sig[sidx];
  if (mode == 0) {
#pragma unroll
    for (int i = 0; i < 4; ++i)
#pragma unroll
      for (int j = 0; j < 4; ++j) {
        int co = co0 + j * 16 + ln;
        int pb = n0 + i * 16 + qd * 4;
#pragma unroll
        for (int r = 0; r < 4; ++r)
          out[((size_t)(b * 4096 + pb + r)) * 256 + co] = acc[i][j][r] * isg;
      }
  } else {
#pragma unroll
    for (int i = 0; i < 4; ++i)
#pragma unroll
      for (int j = 0; j < 4; ++j) {
        int co = co0 + j * 16 + ln;
        int pb = n0 + i * 16 + qd * 4;
        float4* rp = (float4*)&out[((size_t)(b * 256 + co) << 12) + pb];
        float4 v = *rp;
        v.x += acc[i][j][0] * isg; v.y += acc[i][j][1] * isg;
        v.z += acc[i][j][2] * isg; v.w += acc[i][j][3] * isg;
        *rp = v;
      }
  }
}

// ---- shortcut 1x1: res[b][co][n] = isg * sum_c w3[co][c] y_t[b][n][c] ----
__global__ __launch_bounds__(64, 2) void scgemm_mfma_kernel(
    const unsigned short* __restrict__ y_t, const unsigned short* __restrict__ w3b,
    const float* __restrict__ inv_sig, float* __restrict__ res) {
  int b = blockIdx.z;
  int co0 = blockIdx.y * 64;
  int n0 = blockIdx.x * 64;
  __shared__ short Ys[64 * 40];
  int lane = threadIdx.x;
  int ln = lane & 15, qd = lane >> 4;
  int part = lane & 3, r4 = lane >> 2;
  f4 z = {0.f, 0.f, 0.f, 0.f};
  f4 acc[4][4];
#pragma unroll
  for (int i = 0; i < 4; ++i)
#pragma unroll
    for (int j = 0; j < 4; ++j) acc[i][j] = z;
  for (int k0 = 0; k0 < 512; k0 += 32) {
#pragma unroll
    for (int it = 0; it < 4; ++it) {
      int rr = r4 + it * 16;
      bh8 v = *(const bh8*)&y_t[((size_t)(b * 4096 + n0 + rr)) * 512 + k0 + part * 8];
      *(bh8*)&Ys[rr * 40 + part * 8] = v;
    }
    __syncthreads();
    bh8 bw[4];
#pragma unroll
    for (int j = 0; j < 4; ++j)
      bw[j] = *(const bh8*)&w3b[((size_t)(co0 + j * 16 + ln)) * 512 + k0 + qd * 8];
#pragma unroll
    for (int i = 0; i < 4; ++i) {
      bh8 a = *(const bh8*)&Ys[(i * 16 + ln) * 40 + qd * 8];
#pragma unroll
      for (int j = 0; j < 4; ++j)
        acc[i][j] = __builtin_amdgcn_mfma_f32_16x16x32_bf16(a, bw[j], acc[i][j], 0, 0, 0);
    }
    __syncthreads();
  }
  float isg = inv_sig[2];
#pragma unroll
  for (int i = 0; i < 4; ++i)
#pragma unroll
    for (int j = 0; j < 4; ++j) {
      int co = co0 + j * 16 + ln;
      int pb = n0 + i * 16 + qd * 4;
      float4 o;
      o.x = acc[i][j][0] * isg; o.y = acc[i][j][1] * isg;
      o.z = acc[i][j][2] * isg; o.w = acc[i][j][3] * isg;
      *(float4*)&res[((size_t)(b * 256 + co) << 12) + pb] = o;
    }
}

extern "C" void kernel_launch(void* const* d_in, const int* in_sizes, int n_in,
                              void* d_out, int out_size, void* d_ws, size_t ws_size,
                              hipStream_t stream) {
  const float* x     = (const float*)d_in[0];
  const float* pre   = (const float*)d_in[1];
  const float* mask  = (const float*)d_in[2];
  const float* qw    = (const float*)d_in[3];
  const float* gamma = (const float*)d_in[4];
  const float* alpha = (const float*)d_in[5];
  const float* bn1s  = (const float*)d_in[6];
  const float* bn1b  = (const float*)d_in[7];
  const float* c1w   = (const float*)d_in[8];
  const float* u1    = (const float*)d_in[9];
  const float* bn2s  = (const float*)d_in[11];
  const float* bn2b  = (const float*)d_in[12];
  const float* c2w   = (const float*)d_in[13];
  const float* u2    = (const float*)d_in[14];
  const float* byw   = (const float*)d_in[16];
  const float* u3    = (const float*)d_in[17];

  float* res = (float*)d_out;                 // 2*256*4096
  float* att = res + (size_t)2 * 256 * 4096;  // 2*4096*4096

  char* W = (char*)d_ws;
  float* inv_sig = (float*)(W + 0);
  float* mean1   = (float*)(W + 64);
  float* rstd1   = (float*)(W + 2112);
  float* mean2   = (float*)(W + 4160);
  float* rstd2   = (float*)(W + 5184);
  float* part    = (float*)(W + 8192);            // 64*2*512 f32
  float* q       = (float*)(W + 270336);          // 2 MB
  unsigned short* x_bf = (unsigned short*)(W + 2367488);
  unsigned short* p_bf = (unsigned short*)(W + 6561792);
  unsigned short* y_t  = (unsigned short*)(W + 10756096);   // [2][4096][512]
  unsigned short* act1 = (unsigned short*)(W + 19144704);   // [2][4096][512]
  float* h1_t          = (float*)(W + 27533312);            // [2][4096][256]
  unsigned short* act2 = (unsigned short*)(W + 35921920);   // [2][4096][256]
  unsigned short* w1t  = (unsigned short*)(W + 40116224);   // [9][256][512]
  unsigned short* w2t  = (unsigned short*)(W + 42475520);   // [9][256][256]
  unsigned short* w3b  = (unsigned short*)(W + 43655168);   // [256][512]

  hipLaunchKernelGGL(sn3_kernel, dim3(3), dim3(256), 0, stream,
                     c1w, u1, c2w, u2, byw, u3, inv_sig);
  hipLaunchKernelGGL(cast_xp_kernel, dim3(1024, 2), dim3(256), 0, stream, x, pre, x_bf, p_bf);
  hipLaunchKernelGGL(transpose_w_kernel, dim3(4608), dim3(256), 0, stream, c1w, w1t, 512);
  hipLaunchKernelGGL(transpose_w_kernel, dim3(2304), dim3(256), 0, stream, c2w, w2t, 256);
  hipLaunchKernelGGL(cast_w3_kernel, dim3(64), dim3(256), 0, stream, byw, w3b);
  hipLaunchKernelGGL(qconv_kernel, dim3(2048), dim3(256), 0, stream, x, qw, q);
  hipLaunchKernelGGL(energy_kernel, dim3(64, 64, 2), dim3(256), 0, stream, q, att);
  hipLaunchKernelGGL(softmax_kernel, dim3(8192), dim3(256), 0, stream, att);
  hipLaunchKernelGGL(outcf_mfma_kernel, dim3(64, 4, 2), dim3(64), 0, stream,
                     x_bf, p_bf, x, pre, att, mask, gamma, alpha, y_t);
  hipLaunchKernelGGL(bn_part_kernel, dim3(64), dim3(256), 0, stream,
                     (const void*)y_t, 1, 512, 128, part);
  hipLaunchKernelGGL(bn_finish_kernel, dim3(1), dim3(256), 0, stream,
                     part, 512, 64, 1.0f / 8192.0f, mean1, rstd1);
  hipLaunchKernelGGL(bn_act_bf_kernel, dim3(8192), dim3(256), 0, stream,
                     y_t, act1, mean1, rstd1, bn1s, bn1b, 511);
  hipLaunchKernelGGL(conv3x3_mfma_kernel, dim3(64, 4, 2), dim3(64), 0, stream,
                     act1, w1t, inv_sig, 0, 512, 0, h1_t);
  hipLaunchKernelGGL(bn_part_kernel, dim3(64), dim3(256), 0, stream,
                     (const void*)h1_t, 0, 256, 128, part);
  hipLaunchKernelGGL(bn_finish_kernel, dim3(1), dim3(256), 0, stream,
                     part, 256, 64, 1.0f / 8192.0f, mean2, rstd2);
  hipLaunchKernelGGL(bn_act_f_kernel, dim3(2048), dim3(256), 0, stream,
                     h1_t, act2, mean2, rstd2, bn2s, bn2b, 255);
  hipLaunchKernelGGL(scgemm_mfma_kernel, dim3(64, 4, 2), dim3(64), 0, stream,
                     y_t, w3b, inv_sig, res);
  hipLaunchKernelGGL(conv3x3_mfma_kernel, dim3(64, 4, 2), dim3(64), 0, stream,
                     act2, w2t, inv_sig, 1, 256, 1, res);
}

// Round 3
// 851.091 us; speedup vs baseline: 3.6457x; 1.4909x over previous
//
#include <hip/hip_runtime.h>
#include <cstddef>

// B=2, C=256, W=H=64, N=4096, Cq=64
// outputs: res (2*256*4096) then attention (2*4096*4096), fp32

typedef __attribute__((ext_vector_type(8))) short bh8;   // 8 bf16 (4 VGPR)
typedef __attribute__((ext_vector_type(4))) short bh4;   // 4 bf16 (8B)
typedef __attribute__((ext_vector_type(4))) float f4;    // MFMA acc

static __device__ __forceinline__ short f2bf(float f) {
  unsigned u = __float_as_uint(f);
  unsigned r = (u + 0x7fffu + ((u >> 16) & 1u)) >> 16;
  return (short)r;
}
static __device__ __forceinline__ float bf2f(unsigned short s) {
  return __uint_as_float(((unsigned)s) << 16);
}

__device__ __forceinline__ float blk_sum256(float v, float* sm) {
#pragma unroll
  for (int o = 32; o > 0; o >>= 1) v += __shfl_down(v, o, 64);
  __syncthreads();
  if ((threadIdx.x & 63) == 0) sm[threadIdx.x >> 6] = v;
  __syncthreads();
  return sm[0] + sm[1] + sm[2] + sm[3];
}

__device__ __forceinline__ float blk_max256(float v, float* sm) {
#pragma unroll
  for (int o = 32; o > 0; o >>= 1) v = fmaxf(v, __shfl_down(v, o, 64));
  __syncthreads();
  if ((threadIdx.x & 63) == 0) sm[threadIdx.x >> 6] = v;
  __syncthreads();
  return fmaxf(fmaxf(sm[0], sm[1]), fmaxf(sm[2], sm[3]));
}

// ==== spectral norm, parallel: t = W^T u ====
__global__ __launch_bounds__(256) void snA_kernel(
    const float* __restrict__ w1, const float* __restrict__ u1,
    const float* __restrict__ w2, const float* __restrict__ u2,
    const float* __restrict__ w3, const float* __restrict__ u3,
    float* __restrict__ t1, float* __restrict__ t2, float* __restrict__ t3) {
  int g = blockIdx.x * 256 + threadIdx.x;   // 0..7423
  const float* W; const float* u; float* t; int K; int j;
  if (g < 4608)      { W = w1; u = u1; t = t1; K = 4608; j = g; }
  else if (g < 6912) { W = w2; u = u2; t = t2; K = 2304; j = g - 4608; }
  else if (g < 7424) { W = w3; u = u3; t = t3; K = 512;  j = g - 6912; }
  else return;
  float a = 0.f;
  for (int i = 0; i < 256; ++i) a += W[(size_t)i * K + j] * u[i];
  t[j] = a;
}

// ==== invn[w] = 1/(||t||+eps) ====
__global__ __launch_bounds__(256) void snN_kernel(
    const float* __restrict__ t1, const float* __restrict__ t2,
    const float* __restrict__ t3, float* __restrict__ invn) {
  __shared__ float red[4];
  const float* t; int K;
  if (blockIdx.x == 0)      { t = t1; K = 4608; }
  else if (blockIdx.x == 1) { t = t2; K = 2304; }
  else                      { t = t3; K = 512;  }
  float ss = 0.f;
  for (int j = threadIdx.x; j < K; j += 256) { float v = t[j]; ss += v * v; }
  ss = blk_sum256(ss, red);
  if (threadIdx.x == 0) invn[blockIdx.x] = 1.0f / (sqrtf(ss) + 1e-12f);
}

// ==== st = W t (wave per row) ====
__global__ __launch_bounds__(256) void snB_kernel(
    const float* __restrict__ w1, const float* __restrict__ t1,
    const float* __restrict__ w2, const float* __restrict__ t2,
    const float* __restrict__ w3, const float* __restrict__ t3,
    float* __restrict__ st) {
  int blk = blockIdx.x;                // 192 blocks: w*64 + rowgrp
  int w = blk >> 6;
  const float* W; const float* t; int K;
  if (w == 0)      { W = w1; t = t1; K = 4608; }
  else if (w == 1) { W = w2; t = t2; K = 2304; }
  else             { W = w3; t = t3; K = 512;  }
  int lane = threadIdx.x & 63, wave = threadIdx.x >> 6;
  int row = (blk & 63) * 4 + wave;
  const float* Wr = W + (size_t)row * K;
  float a = 0.f;
  for (int j = lane; j < K; j += 64) a += Wr[j] * t[j];
#pragma unroll
  for (int o = 32; o > 0; o >>= 1) a += __shfl_down(a, o, 64);
  if (lane == 0) st[w * 256 + row] = a;
}

// ==== sigma -> inv_sig ====
__global__ __launch_bounds__(256) void snC_kernel(
    const float* __restrict__ st, const float* __restrict__ invn,
    float* __restrict__ inv_sig) {
  __shared__ float red[4];
  int w = blockIdx.x;
  float v = st[w * 256 + threadIdx.x];
  float ss = blk_sum256(v * v, red);
  if (threadIdx.x == 0) {
    float in = invn[w];
    float s2 = in * in * ss;            // ||s||^2
    float sn = in * sqrtf(ss);          // ||s||
    float sigma = s2 / (sn + 1e-12f);
    inv_sig[w] = 1.0f / sigma;
  }
}

// ---- cast x / pre to bf16 (same [c][n] layout) ----
__global__ __launch_bounds__(256) void cast_xp_kernel(
    const float* __restrict__ x, const float* __restrict__ pre,
    unsigned short* __restrict__ xb, unsigned short* __restrict__ pb) {
  int i = blockIdx.x * 256 + threadIdx.x;   // 8 elems per thread
  const float* s = blockIdx.y ? pre : x;
  unsigned short* d = blockIdx.y ? pb : xb;
  float4 v0 = ((const float4*)s)[i * 2];
  float4 v1 = ((const float4*)s)[i * 2 + 1];
  bh8 o = { f2bf(v0.x), f2bf(v0.y), f2bf(v0.z), f2bf(v0.w),
            f2bf(v1.x), f2bf(v1.y), f2bf(v1.z), f2bf(v1.w) };
  *(bh8*)&d[(size_t)i * 8] = o;
}

// ---- transpose conv weights OIHW -> [tap][co][ci], bf16 ----
__global__ __launch_bounds__(256) void transpose_w_kernel(
    const float* __restrict__ src, unsigned short* __restrict__ dst, int Cin) {
  int i = blockIdx.x * 256 + threadIdx.x;   // linear over 9*256*Cin
  int ci = i % Cin;
  int co = (i / Cin) & 255;
  int t = i / (Cin * 256);
  dst[i] = (unsigned short)f2bf(src[((size_t)co * Cin + ci) * 9 + t]);
}

// ---- cast by_w [256][512] to bf16 ----
__global__ __launch_bounds__(256) void cast_w3_kernel(
    const float* __restrict__ src, unsigned short* __restrict__ dst) {
  int i = blockIdx.x * 256 + threadIdx.x;   // 8 elems per thread
  float4 v0 = ((const float4*)src)[i * 2];
  float4 v1 = ((const float4*)src)[i * 2 + 1];
  bh8 o = { f2bf(v0.x), f2bf(v0.y), f2bf(v0.z), f2bf(v0.w),
            f2bf(v1.x), f2bf(v1.y), f2bf(v1.z), f2bf(v1.w) };
  *(bh8*)&dst[(size_t)i * 8] = o;
}

// ---- q = 1x1 conv (f32) ----
__global__ __launch_bounds__(256) void qconv_kernel(
    const float* __restrict__ x, const float* __restrict__ qw, float* __restrict__ q) {
  int gid = blockIdx.x;
  int ntile = gid & 15;
  int cq = (gid >> 4) & 63;
  int b = gid >> 10;
  int n = (ntile << 8) + threadIdx.x;
  const float* xb = x + ((size_t)b << 20) + n;
  const float* wr = qw + cq * 256;
  float acc = 0.f;
#pragma unroll 8
  for (int c = 0; c < 256; ++c) acc += wr[c] * xb[(size_t)c << 12];
  q[(((size_t)(b * 64 + cq)) << 12) + n] = acc;
}

// ---- energy (f32, exact since attention is a checked output) ----
__global__ __launch_bounds__(256) void energy_kernel(
    const float* __restrict__ q, float* __restrict__ att) {
  int b = blockIdx.z;
  int m0 = blockIdx.x * 64, n0 = blockIdx.y * 64;
  __shared__ float Qn[64][65];
  __shared__ float Qm[64][65];
  int tid = threadIdx.x;
  int col = tid & 63;
#pragma unroll
  for (int p = 0; p < 16; ++p) {
    int k = p * 4 + (tid >> 6);
    const float* qr = q + (((size_t)(b * 64 + k)) << 12);
    Qn[k][col] = qr[n0 + col];
    Qm[k][col] = qr[m0 + col];
  }
  __syncthreads();
  int tx = tid & 15, ty = tid >> 4;
  float acc[4][4] = {};
#pragma unroll
  for (int k = 0; k < 64; ++k) {
    float a[4], bb[4];
#pragma unroll
    for (int i = 0; i < 4; ++i) a[i] = Qn[k][ty * 4 + i];
#pragma unroll
    for (int j = 0; j < 4; ++j) bb[j] = Qm[k][tx * 4 + j];
#pragma unroll
    for (int i = 0; i < 4; ++i)
#pragma unroll
      for (int j = 0; j < 4; ++j) acc[i][j] += a[i] * bb[j];
  }
  size_t base = ((size_t)b << 24);
#pragma unroll
  for (int i = 0; i < 4; ++i) {
    size_t off = base + (((size_t)(n0 + ty * 4 + i)) << 12) + m0 + tx * 4;
    float4 o; o.x = acc[i][0]; o.y = acc[i][1]; o.z = acc[i][2]; o.w = acc[i][3];
    *(float4*)&att[off] = o;
  }
}

// ---- softmax in place over last dim 4096 ----
__global__ __launch_bounds__(256) void softmax_kernel(float* __restrict__ att) {
  __shared__ float red[4];
  size_t row = blockIdx.x;
  float4* rp4 = (float4*)(att + (row << 12));
  int tid = threadIdx.x;
  float4 v[4];
#pragma unroll
  for (int i = 0; i < 4; ++i) v[i] = rp4[tid + (i << 8)];
  float mx = -INFINITY;
#pragma unroll
  for (int i = 0; i < 4; ++i)
    mx = fmaxf(mx, fmaxf(fmaxf(v[i].x, v[i].y), fmaxf(v[i].z, v[i].w)));
  mx = blk_max256(mx, red);
  float s = 0.f;
#pragma unroll
  for (int i = 0; i < 4; ++i) {
    v[i].x = __expf(v[i].x - mx); v[i].y = __expf(v[i].y - mx);
    v[i].z = __expf(v[i].z - mx); v[i].w = __expf(v[i].w - mx);
    s += v[i].x + v[i].y + v[i].z + v[i].w;
  }
  s = blk_sum256(s, red);
  float inv = 1.0f / s;
#pragma unroll
  for (int i = 0; i < 4; ++i) {
    v[i].x *= inv; v[i].y *= inv; v[i].z *= inv; v[i].w *= inv;
    rp4[tid + (i << 8)] = v[i];
  }
}

// ---- fused out/cf MFMA GEMM: 1 wave per block, 64c x 64j tile ----
__global__ __launch_bounds__(64, 2) void outcf_mfma_kernel(
    const unsigned short* __restrict__ xb, const unsigned short* __restrict__ pb,
    const float* __restrict__ x, const float* __restrict__ pre,
    const float* __restrict__ att, const float* __restrict__ mask,
    const float* __restrict__ gamma_p, const float* __restrict__ alpha_p,
    unsigned short* __restrict__ y_t) {
  int b = blockIdx.z;
  int c0 = blockIdx.y * 64;
  int j0 = blockIdx.x * 64;
  __shared__ short Xs[64 * 40];
  __shared__ short Ps[64 * 40];
  __shared__ short As[64 * 40];
  int lane = threadIdx.x;
  int ln = lane & 15, qd = lane >> 4;
  f4 z = {0.f, 0.f, 0.f, 0.f};
  f4 accO[4][4], accC[4][4];
#pragma unroll
  for (int i = 0; i < 4; ++i)
#pragma unroll
    for (int j = 0; j < 4; ++j) { accO[i][j] = z; accC[i][j] = z; }
  int part = lane & 3, r4 = lane >> 2;
  int part8 = lane & 7, r8 = lane >> 3;
  for (int k0 = 0; k0 < 4096; k0 += 32) {
#pragma unroll
    for (int it = 0; it < 4; ++it) {
      int rr = r4 + it * 16;
      bh8 xv = *(const bh8*)&xb[((size_t)(b * 256 + c0 + rr) << 12) + k0 + part * 8];
      bh8 pv = *(const bh8*)&pb[((size_t)(b * 256 + c0 + rr) << 12) + k0 + part * 8];
      *(bh8*)&Xs[rr * 40 + part * 8] = xv;
      *(bh8*)&Ps[rr * 40 + part * 8] = pv;
    }
#pragma unroll
    for (int it = 0; it < 8; ++it) {
      int rr = r8 + it * 8;
      float4 v = *(const float4*)&att[((size_t)b << 24) + ((size_t)(j0 + rr) << 12) + k0 + part8 * 4];
      bh4 o = { f2bf(v.x), f2bf(v.y), f2bf(v.z), f2bf(v.w) };
      *(bh4*)&As[rr * 40 + part8 * 4] = o;
    }
    __syncthreads();
    bh8 bf[4];
#pragma unroll
    for (int j = 0; j < 4; ++j)
      bf[j] = *(const bh8*)&As[(j * 16 + ln) * 40 + qd * 8];
#pragma unroll
    for (int i = 0; i < 4; ++i) {
      bh8 ax = *(const bh8*)&Xs[(i * 16 + ln) * 40 + qd * 8];
      bh8 ap = *(const bh8*)&Ps[(i * 16 + ln) * 40 + qd * 8];
#pragma unroll
      for (int j = 0; j < 4; ++j) {
        accO[i][j] = __builtin_amdgcn_mfma_f32_16x16x32_bf16(ax, bf[j], accO[i][j], 0, 0, 0);
        accC[i][j] = __builtin_amdgcn_mfma_f32_16x16x32_bf16(ap, bf[j], accC[i][j], 0, 0, 0);
      }
    }
    __syncthreads();
  }
  float g = gamma_p[0], al = alpha_p[0];
#pragma unroll
  for (int j = 0; j < 4; ++j) {
    int jp = j0 + j * 16 + ln;
    float mv = mask[(b << 12) + jp];
#pragma unroll
    for (int i = 0; i < 4; ++i) {
      int cb = c0 + i * 16 + qd * 4;
      bh4 oY, oC;
#pragma unroll
      for (int r = 0; r < 4; ++r) {
        float xo = x[((size_t)(b * 256 + cb + r) << 12) + jp];
        float po = pre[((size_t)(b * 256 + cb + r) << 12) + jp];
        oY[r] = f2bf(g * accO[i][j][r] + xo);
        oC[r] = f2bf(al * (1.f - mv) * accC[i][j][r] + mv * po);
      }
      size_t rowb = ((size_t)b * 4096 + jp) * 512;
      *(bh4*)&y_t[rowb + cb] = oY;
      *(bh4*)&y_t[rowb + 256 + cb] = oC;
    }
  }
}

// ---- BN stats phase 1 ----
__global__ __launch_bounds__(256) void bn_part_kernel(
    const void* __restrict__ src, int isbf, int C, int rows_per_slab,
    float* __restrict__ part) {
  int slab = blockIdx.x;
  int r0 = slab * rows_per_slab;
  for (int co = threadIdx.x; co < C; co += 256) {
    float s = 0.f, ss = 0.f;
    if (isbf) {
      const unsigned short* p = (const unsigned short*)src;
      for (int r = 0; r < rows_per_slab; ++r) {
        float v = bf2f(p[(size_t)(r0 + r) * C + co]); s += v; ss += v * v;
      }
    } else {
      const float* p = (const float*)src;
      for (int r = 0; r < rows_per_slab; ++r) {
        float v = p[(size_t)(r0 + r) * C + co]; s += v; ss += v * v;
      }
    }
    part[(size_t)(slab * 2) * C + co] = s;
    part[(size_t)(slab * 2 + 1) * C + co] = ss;
  }
}

// ---- BN stats phase 2 ----
__global__ __launch_bounds__(256) void bn_finish_kernel(
    const float* __restrict__ part, int C, int slabs, float inv_count,
    float* __restrict__ mean, float* __restrict__ rstd) {
  for (int co = threadIdx.x; co < C; co += 256) {
    float s = 0.f, ss = 0.f;
    for (int sl = 0; sl < slabs; ++sl) {
      s += part[(size_t)(sl * 2) * C + co];
      ss += part[(size_t)(sl * 2 + 1) * C + co];
    }
    float m = s * inv_count;
    float var = ss * inv_count - m * m;
    mean[co] = m;
    rstd[co] = rsqrtf(var + 1e-5f);
  }
}

// ---- BN apply + leaky, bf16 -> bf16 ([n][C] layout) ----
__global__ __launch_bounds__(256) void bn_act_bf_kernel(
    const unsigned short* __restrict__ src, unsigned short* __restrict__ dst,
    const float* __restrict__ mean, const float* __restrict__ rstd,
    const float* __restrict__ sc, const float* __restrict__ bi, int Cm1) {
  int i = blockIdx.x * 256 + threadIdx.x;   // 4 elems
  int ch = (i * 4) & Cm1;
  bh4 v = *(const bh4*)&src[(size_t)i * 4];
  bh4 o;
#pragma unroll
  for (int e = 0; e < 4; ++e) {
    int c = ch + e;
    float a = rstd[c] * sc[c];
    float bb = bi[c] - mean[c] * a;
    float f = bf2f((unsigned short)v[e]) * a + bb;
    f = f > 0.f ? f : 0.01f * f;
    o[e] = f2bf(f);
  }
  *(bh4*)&dst[(size_t)i * 4] = o;
}

// ---- BN apply + leaky, f32 -> bf16 ----
__global__ __launch_bounds__(256) void bn_act_f_kernel(
    const float* __restrict__ src, unsigned short* __restrict__ dst,
    const float* __restrict__ mean, const float* __restrict__ rstd,
    const float* __restrict__ sc, const float* __restrict__ bi, int Cm1) {
  int i = blockIdx.x * 256 + threadIdx.x;   // 4 elems
  int ch = (i * 4) & Cm1;
  float4 v = ((const float4*)src)[i];
  float vv[4] = {v.x, v.y, v.z, v.w};
  bh4 o;
#pragma unroll
  for (int e = 0; e < 4; ++e) {
    int c = ch + e;
    float a = rstd[c] * sc[c];
    float bb = bi[c] - mean[c] * a;
    float f = vv[e] * a + bb;
    f = f > 0.f ? f : 0.01f * f;
    o[e] = f2bf(f);
  }
  *(bh4*)&dst[(size_t)i * 4] = o;
}

// ---- 3x3 conv as 9 accumulated MFMA GEMMs over flat-shifted rows ----
__global__ __launch_bounds__(64, 2) void conv3x3_mfma_kernel(
    const unsigned short* __restrict__ act_t, const unsigned short* __restrict__ wt,
    const float* __restrict__ inv_sig, int sidx, int Cin, int mode,
    float* __restrict__ out) {
  int b = blockIdx.z;
  int co0 = blockIdx.y * 64;
  int n0 = blockIdx.x * 64;
  __shared__ short act_s[194 * 40];
  int lane = threadIdx.x;
  int ln = lane & 15, qd = lane >> 4;
  int part = lane & 3, r4 = lane >> 2;
  f4 z = {0.f, 0.f, 0.f, 0.f};
  f4 acc[4][4];
#pragma unroll
  for (int i = 0; i < 4; ++i)
#pragma unroll
    for (int j = 0; j < 4; ++j) acc[i][j] = z;
  bh8 zf = {};
  int nchunk = Cin >> 5;
  for (int cc = 0; cc < nchunk; ++cc) {
    int ci0 = cc << 5;
#pragma unroll
    for (int it = 0; it < 13; ++it) {
      int rr = r4 + it * 16;
      if (rr < 194) {
        int flat = n0 - 65 + rr;
        bh8 v = {};
        if ((unsigned)flat < 4096u)
          v = *(const bh8*)&act_t[((size_t)(b * 4096 + flat)) * Cin + ci0 + part * 8];
        *(bh8*)&act_s[rr * 40 + part * 8] = v;
      }
    }
    __syncthreads();
#pragma unroll
    for (int t = 0; t < 9; ++t) {
      int dy = t / 3, dx = t - dy * 3;
      int off = (dy - 1) * 64 + (dx - 1);
      bh8 bw[4];
#pragma unroll
      for (int j = 0; j < 4; ++j) {
        int co = co0 + j * 16 + ln;
        bw[j] = *(const bh8*)&wt[((size_t)(t * 256 + co)) * Cin + ci0 + qd * 8];
      }
#pragma unroll
      for (int i = 0; i < 4; ++i) {
        int px = i * 16 + ln;
        bh8 a = *(const bh8*)&act_s[(65 + off + px) * 40 + qd * 8];
        if (dx == 0 && px == 0) a = zf;
        if (dx == 2 && px == 63) a = zf;
#pragma unroll
        for (int j = 0; j < 4; ++j)
          acc[i][j] = __builtin_amdgcn_mfma_f32_16x16x32_bf16(a, bw[j], acc[i][j], 0, 0, 0);
      }
    }
    __syncthreads();
  }
  float isg = inv_sig[sidx];
  if (mode == 0) {
#pragma unroll
    for (int i = 0; i < 4; ++i)
#pragma unroll
      for (int j = 0; j < 4; ++j) {
        int co = co0 + j * 16 + ln;
        int pb = n0 + i * 16 + qd * 4;
#pragma unroll
        for (int r = 0; r < 4; ++r)
          out[((size_t)(b * 4096 + pb + r)) * 256 + co] = acc[i][j][r] * isg;
      }
  } else {
#pragma unroll
    for (int i = 0; i < 4; ++i)
#pragma unroll
      for (int j = 0; j < 4; ++j) {
        int co = co0 + j * 16 + ln;
        int pb = n0 + i * 16 + qd * 4;
        float4* rp = (float4*)&out[((size_t)(b * 256 + co) << 12) + pb];
        float4 v = *rp;
        v.x += acc[i][j][0] * isg; v.y += acc[i][j][1] * isg;
        v.z += acc[i][j][2] * isg; v.w += acc[i][j][3] * isg;
        *rp = v;
      }
  }
}

// ---- shortcut 1x1 ----
__global__ __launch_bounds__(64, 2) void scgemm_mfma_kernel(
    const unsigned short* __restrict__ y_t, const unsigned short* __restrict__ w3b,
    const float* __restrict__ inv_sig, float* __restrict__ res) {
  int b = blockIdx.z;
  int co0 = blockIdx.y * 64;
  int n0 = blockIdx.x * 64;
  __shared__ short Ys[64 * 40];
  int lane = threadIdx.x;
  int ln = lane & 15, qd = lane >> 4;
  int part = lane & 3, r4 = lane >> 2;
  f4 z = {0.f, 0.f, 0.f, 0.f};
  f4 acc[4][4];
#pragma unroll
  for (int i = 0; i < 4; ++i)
#pragma unroll
    for (int j = 0; j < 4; ++j) acc[i][j] = z;
  for (int k0 = 0; k0 < 512; k0 += 32) {
#pragma unroll
    for (int it = 0; it < 4; ++it) {
      int rr = r4 + it * 16;
      bh8 v = *(const bh8*)&y_t[((size_t)(b * 4096 + n0 + rr)) * 512 + k0 + part * 8];
      *(bh8*)&Ys[rr * 40 + part * 8] = v;
    }
    __syncthreads();
    bh8 bw[4];
#pragma unroll
    for (int j = 0; j < 4; ++j)
      bw[j] = *(const bh8*)&w3b[((size_t)(co0 + j * 16 + ln)) * 512 + k0 + qd * 8];
#pragma unroll
    for (int i = 0; i < 4; ++i) {
      bh8 a = *(const bh8*)&Ys[(i * 16 + ln) * 40 + qd * 8];
#pragma unroll
      for (int j = 0; j < 4; ++j)
        acc[i][j] = __builtin_amdgcn_mfma_f32_16x16x32_bf16(a, bw[j], acc[i][j], 0, 0, 0);
    }
    __syncthreads();
  }
  float isg = inv_sig[2];
#pragma unroll
  for (int i = 0; i < 4; ++i)
#pragma unroll
    for (int j = 0; j < 4; ++j) {
      int co = co0 + j * 16 + ln;
      int pb = n0 + i * 16 + qd * 4;
      float4 o;
      o.x = acc[i][j][0] * isg; o.y = acc[i][j][1] * isg;
      o.z = acc[i][j][2] * isg; o.w = acc[i][j][3] * isg;
      *(float4*)&res[((size_t)(b * 256 + co) << 12) + pb] = o;
    }
}

extern "C" void kernel_launch(void* const* d_in, const int* in_sizes, int n_in,
                              void* d_out, int out_size, void* d_ws, size_t ws_size,
                              hipStream_t stream) {
  const float* x     = (const float*)d_in[0];
  const float* pre   = (const float*)d_in[1];
  const float* mask  = (const float*)d_in[2];
  const float* qw    = (const float*)d_in[3];
  const float* gamma = (const float*)d_in[4];
  const float* alpha = (const float*)d_in[5];
  const float* bn1s  = (const float*)d_in[6];
  const float* bn1b  = (const float*)d_in[7];
  const float* c1w   = (const float*)d_in[8];
  const float* u1    = (const float*)d_in[9];
  const float* bn2s  = (const float*)d_in[11];
  const float* bn2b  = (const float*)d_in[12];
  const float* c2w   = (const float*)d_in[13];
  const float* u2    = (const float*)d_in[14];
  const float* byw   = (const float*)d_in[16];
  const float* u3    = (const float*)d_in[17];

  float* res = (float*)d_out;                 // 2*256*4096
  float* att = res + (size_t)2 * 256 * 4096;  // 2*4096*4096

  char* W = (char*)d_ws;
  float* inv_sig = (float*)(W + 0);
  float* mean1   = (float*)(W + 64);
  float* rstd1   = (float*)(W + 2112);
  float* mean2   = (float*)(W + 4160);
  float* rstd2   = (float*)(W + 5184);
  float* part    = (float*)(W + 8192);            // 64*2*512 f32
  float* q       = (float*)(W + 270336);          // 2 MB
  unsigned short* x_bf = (unsigned short*)(W + 2367488);
  unsigned short* p_bf = (unsigned short*)(W + 6561792);
  unsigned short* y_t  = (unsigned short*)(W + 10756096);   // [2][4096][512]
  unsigned short* act1 = (unsigned short*)(W + 19144704);   // [2][4096][512]
  float* h1_t          = (float*)(W + 27533312);            // [2][4096][256]
  unsigned short* act2 = (unsigned short*)(W + 35921920);   // [2][4096][256]
  unsigned short* w1t  = (unsigned short*)(W + 40116224);   // [9][256][512]
  unsigned short* w2t  = (unsigned short*)(W + 42475520);   // [9][256][256]
  unsigned short* w3b  = (unsigned short*)(W + 43655168);   // [256][512]
  float* t1      = (float*)(W + 43917312);        // 4608 f32
  float* t2      = (float*)(W + 43935744);        // 2304 f32
  float* t3      = (float*)(W + 43944960);        // 512 f32
  float* invn    = (float*)(W + 43947008);        // 3 f32
  float* st      = (float*)(W + 43947072);        // 768 f32

  hipLaunchKernelGGL(snA_kernel, dim3(29), dim3(256), 0, stream,
                     c1w, u1, c2w, u2, byw, u3, t1, t2, t3);
  hipLaunchKernelGGL(snN_kernel, dim3(3), dim3(256), 0, stream, t1, t2, t3, invn);
  hipLaunchKernelGGL(snB_kernel, dim3(192), dim3(256), 0, stream,
                     c1w, t1, c2w, t2, byw, t3, st);
  hipLaunchKernelGGL(snC_kernel, dim3(3), dim3(256), 0, stream, st, invn, inv_sig);
  hipLaunchKernelGGL(cast_xp_kernel, dim3(1024, 2), dim3(256), 0, stream, x, pre, x_bf, p_bf);
  hipLaunchKernelGGL(transpose_w_kernel, dim3(4608), dim3(256), 0, stream, c1w, w1t, 512);
  hipLaunchKernelGGL(transpose_w_kernel, dim3(2304), dim3(256), 0, stream, c2w, w2t, 256);
  hipLaunchKernelGGL(cast_w3_kernel, dim3(64), dim3(256), 0, stream, byw, w3b);
  hipLaunchKernelGGL(qconv_kernel, dim3(2048), dim3(256), 0, stream, x, qw, q);
  hipLaunchKernelGGL(energy_kernel, dim3(64, 64, 2), dim3(256), 0, stream, q, att);
  hipLaunchKernelGGL(softmax_kernel, dim3(8192), dim3(256), 0, stream, att);
  hipLaunchKernelGGL(outcf_mfma_kernel, dim3(64, 4, 2), dim3(64), 0, stream,
                     x_bf, p_bf, x, pre, att, mask, gamma, alpha, y_t);
  hipLaunchKernelGGL(bn_part_kernel, dim3(64), dim3(256), 0, stream,
                     (const void*)y_t, 1, 512, 128, part);
  hipLaunchKernelGGL(bn_finish_kernel, dim3(1), dim3(256), 0, stream,
                     part, 512, 64, 1.0f / 8192.0f, mean1, rstd1);
  hipLaunchKernelGGL(bn_act_bf_kernel, dim3(8192), dim3(256), 0, stream,
                     y_t, act1, mean1, rstd1, bn1s, bn1b, 511);
  hipLaunchKernelGGL(conv3x3_mfma_kernel, dim3(64, 4, 2), dim3(64), 0, stream,
                     act1, w1t, inv_sig, 0, 512, 0, h1_t);
  hipLaunchKernelGGL(bn_part_kernel, dim3(64), dim3(256), 0, stream,
                     (const void*)h1_t, 0, 256, 128, part);
  hipLaunchKernelGGL(bn_finish_kernel, dim3(1), dim3(256), 0, stream,
                     part, 256, 64, 1.0f / 8192.0f, mean2, rstd2);
  hipLaunchKernelGGL(bn_act_f_kernel, dim3(2048), dim3(256), 0, stream,
                     h1_t, act2, mean2, rstd2, bn2s, bn2b, 255);
  hipLaunchKernelGGL(scgemm_mfma_kernel, dim3(64, 4, 2), dim3(64), 0, stream,
                     y_t, w3b, inv_sig, res);
  hipLaunchKernelGGL(conv3x3_mfma_kernel, dim3(64, 4, 2), dim3(64), 0, stream,
                     act2, w2t, inv_sig, 1, 256, 1, res);
}